// Round 1
// 92.344 us; speedup vs baseline: 1.0746x; 1.0746x over previous
//
#include <hip/hip_runtime.h>

// Chamfer distance: B=4, S=4, N=M=4096, D=3, fp32 in/out.
//
// R8: move the 537M 3-D dot products from the FP32 VALU (157 TF, measured
// floor ~24 us) to the MFMA pipe (2495 TF) with a precision-preserving
// bf16 triple-split (3xTF32 style):
//   v = h + m + l (bf16 each); keep products hh,hm,mh,hl,lh,mm per coord
//   -> per-product rel err ~2^-26 (better than fp32 multiply).
// K-slot layout of mfma_f32_16x16x32_bf16 (21/32 slots used):
//   k0..5  x: A=[h,h,m,h,l,m] B=[h,m,h,l,h,m]
//   k6..11 y, k12..17 z (same pattern)
//   k18..20 bias: A=[1,1,1], B=[wh,wm,wl], w = -0.5*|r|^2
// g = q.r + w per 16q x 16r tile in ONE MFMA; min d2 = max(x2 - 2*max g, 0).
//
// Decomposition: 512-thr blocks (8 waves), wave holds 8 A-frags (128 q) in
// regs; block = 1024 q x 1024 refs; grid 4x4x32 = 512 blocks = 2/CU
// (16 waves/CU, 2x64KB LDS). Ref split -> per-query partial max in ws
// (2 MB), combined by a small finalize kernel.
// Pipe budget/CU: MFMA 8192 insts ~4.1us, DS 1024 ds_read_b128 ~4-5us,
// VALU 16 max3 per tile-pair ~3.4us -- overlapped at 4 waves/SIMD.

constexpr int B = 4, S = 4, NPTS = 4096, PAIRS = B * S;
constexpr int UNITS = PAIRS * 2;            // (pair, dir)
constexpr int THREADS = 512;                // 8 waves
constexpr int WAVES = THREADS / 64;
constexpr int AFRAGS = 8;                   // 16-query tiles per wave
constexpr int QPB = WAVES * AFRAGS * 16;    // 1024 queries per block
constexpr int QCH = NPTS / QPB;             // 4 query chunks
constexpr int RCH = 4;                      // ref chunks
constexpr int RPB = NPTS / RCH;             // 1024 refs per block
constexpr int RTILES = RPB / 16;            // 64 B-tiles per block
constexpr unsigned short BF16_ONE = 0x3F80;

typedef __attribute__((ext_vector_type(8))) short bf16x8;
typedef __attribute__((ext_vector_type(4))) float f32x4;
typedef __attribute__((ext_vector_type(4))) unsigned int u32x4;

static __device__ inline unsigned short bf16_rne(float v) {
  unsigned int u = __builtin_bit_cast(unsigned int, v);
  u += 0x7FFFu + ((u >> 16) & 1u);
  return (unsigned short)(u >> 16);
}
static __device__ inline float bf16f(unsigned short h) {
  unsigned int u = (unsigned int)h << 16;
  return __builtin_bit_cast(float, u);
}
static __device__ inline unsigned int bpack(unsigned short lo, unsigned short hi) {
  return (unsigned int)lo | ((unsigned int)hi << 16);
}

struct Split3 { unsigned short h, m, l; };
static __device__ inline Split3 split3(float v) {
  Split3 s;
  s.h = bf16_rne(v);
  float r = v - bf16f(s.h);
  s.m = bf16_rne(r);
  r -= bf16f(s.m);
  s.l = bf16_rne(r);
  return s;
}

// A-operand: lane l holds row i = l&15, k = (l>>4)*8 + e.
// B-operand: lane l holds col j = l&15, k = (l>>4)*8 + e.
// D:         lane l holds col j = l&15, row = (l>>4)*4 + reg  [m89-verified].

__global__ __launch_bounds__(THREADS, 4)
void chamfer_mfma_main(const float* __restrict__ out_pts,
                       const float* __restrict__ tgt_pts,
                       float* __restrict__ part) {
  const int t = threadIdx.x;
  const int l = t & 63;
  const int wid = t >> 6;
  const int qc = blockIdx.x;      // 0..3
  const int rc = blockIdx.y;      // 0..3
  const int unit = blockIdx.z;    // 0..31
  const int pair = unit >> 1, dir = unit & 1;

  const float* qpts = (dir == 0 ? out_pts : tgt_pts) + (size_t)pair * NPTS * 3;
  const float* rpts = (dir == 0 ? tgt_pts : out_pts) + (size_t)pair * NPTS * 3;

  __shared__ u32x4 lds[RTILES * 64];  // 64 KB: 64 tiles x 64 lanes x 16B

  // ---- Phase 1: build A-frag records for this block's 1024 queries.
  {
    const int q0 = qc * QPB;
    #pragma unroll
    for (int rep = 0; rep < QPB / THREADS; ++rep) {
      const int j = t + rep * THREADS;
      const float x = qpts[3 * (q0 + j)];
      const float y = qpts[3 * (q0 + j) + 1];
      const float z = qpts[3 * (q0 + j) + 2];
      const Split3 sx = split3(x), sy = split3(y), sz = split3(z);
      u32x4* base = lds + (j >> 4) * 64 + (j & 15);
      const u32x4 g0 = {bpack(sx.h, sx.h), bpack(sx.m, sx.h),
                        bpack(sx.l, sx.m), bpack(sy.h, sy.h)};
      const u32x4 g1 = {bpack(sy.m, sy.h), bpack(sy.l, sy.m),
                        bpack(sz.h, sz.h), bpack(sz.m, sz.h)};
      const u32x4 g2 = {bpack(sz.l, sz.m), bpack(BF16_ONE, BF16_ONE),
                        bpack(BF16_ONE, 0), 0u};
      const u32x4 g3 = {0u, 0u, 0u, 0u};
      base[0] = g0; base[16] = g1; base[32] = g2; base[48] = g3;
    }
  }
  __syncthreads();

  bf16x8 a[AFRAGS];
  #pragma unroll
  for (int m = 0; m < AFRAGS; ++m)
    a[m] = ((const bf16x8*)lds)[(wid * AFRAGS + m) * 64 + l];
  __syncthreads();

  // ---- Phase 2: build B-frag records for this block's 1024 refs.
  {
    const int r0 = rc * RPB;
    #pragma unroll
    for (int rep = 0; rep < RPB / THREADS; ++rep) {
      const int j = t + rep * THREADS;
      const float x = rpts[3 * (r0 + j)];
      const float y = rpts[3 * (r0 + j) + 1];
      const float z = rpts[3 * (r0 + j) + 2];
      const float w = -0.5f * (x * x + y * y + z * z);
      const Split3 sx = split3(x), sy = split3(y), sz = split3(z), sw = split3(w);
      u32x4* base = lds + (j >> 4) * 64 + (j & 15);
      const u32x4 g0 = {bpack(sx.h, sx.m), bpack(sx.h, sx.l),
                        bpack(sx.h, sx.m), bpack(sy.h, sy.m)};
      const u32x4 g1 = {bpack(sy.h, sy.l), bpack(sy.h, sy.m),
                        bpack(sz.h, sz.m), bpack(sz.h, sz.l)};
      const u32x4 g2 = {bpack(sz.h, sz.m), bpack(sw.h, sw.m),
                        bpack(sw.l, 0), 0u};
      const u32x4 g3 = {0u, 0u, 0u, 0u};
      base[0] = g0; base[16] = g1; base[32] = g2; base[48] = g3;
    }
  }
  __syncthreads();

  // ---- Hot loop: per tile-pair: 2 ds_read_b128, 16 MFMA, 16 v_max3.
  f32x4 acc[AFRAGS];
  #pragma unroll
  for (int m = 0; m < AFRAGS; ++m)
    acc[m] = (f32x4){-3.0e38f, -3.0e38f, -3.0e38f, -3.0e38f};

  const f32x4 czero = {0.f, 0.f, 0.f, 0.f};
  const bf16x8* bptr = (const bf16x8*)lds;
  for (int tt = 0; tt < RTILES; tt += 2) {
    const bf16x8 b0 = bptr[tt * 64 + l];
    const bf16x8 b1 = bptr[(tt + 1) * 64 + l];
    #pragma unroll
    for (int m = 0; m < AFRAGS; ++m) {
      const f32x4 d0 = __builtin_amdgcn_mfma_f32_16x16x32_bf16(a[m], b0, czero, 0, 0, 0);
      const f32x4 d1 = __builtin_amdgcn_mfma_f32_16x16x32_bf16(a[m], b1, czero, 0, 0, 0);
      #pragma unroll
      for (int c = 0; c < 4; ++c)
        acc[m][c] = fmaxf(fmaxf(acc[m][c], d0[c]), d1[c]);  // v_max3_f32
    }
  }

  // ---- reduce over the 16 ref-columns (lanes sharing l>>4).
  #pragma unroll
  for (int m = 0; m < AFRAGS; ++m) {
    #pragma unroll
    for (int c = 0; c < 4; ++c) {
      float g = acc[m][c];
      g = fmaxf(g, __shfl_xor(g, 1, 64));
      g = fmaxf(g, __shfl_xor(g, 2, 64));
      g = fmaxf(g, __shfl_xor(g, 4, 64));
      g = fmaxf(g, __shfl_xor(g, 8, 64));
      acc[m][c] = g;
    }
  }
  // every lane writes 2 of the wave's 128 queries: (m = jj>>2 [+4], c = jj&3)
  const int jj = l & 15, hi = l >> 4;
  float v_lo = 0.f, v_hi = 0.f;
  #pragma unroll
  for (int m = 0; m < 4; ++m) {
    #pragma unroll
    for (int c = 0; c < 4; ++c) {
      const bool sel = (jj == m * 4 + c);
      v_lo = sel ? acc[m][c] : v_lo;        // static indices only (no scratch)
      v_hi = sel ? acc[m + 4][c] : v_hi;
    }
  }
  const int q = qc * QPB + wid * (AFRAGS * 16) + (jj >> 2) * 16 + hi * 4 + (jj & 3);
  float* pdst = part + ((size_t)unit * NPTS + q) * RCH + rc;
  pdst[0] = v_lo;
  pdst[64 * RCH] = v_hi;                    // query q + 64
}

// Combine the RCH partial maxima, apply d = max(x2 - 2g, 0), mean-reduce.
__global__ __launch_bounds__(256)
void chamfer_finalize(const float* __restrict__ out_pts,
                      const float* __restrict__ tgt_pts,
                      const float* __restrict__ part,
                      float* __restrict__ out) {
  const int t = threadIdx.x;
  const int blk = blockIdx.x;          // 0..511
  const int unit = blk >> 4;           // 16 blocks per unit, 256 q each
  const int q = (blk & 15) * 256 + t;
  const int pair = unit >> 1, dir = unit & 1;
  const float* qpts = (dir == 0 ? out_pts : tgt_pts) + (size_t)pair * NPTS * 3;

  const f32x4 p = *(const f32x4*)(part + ((size_t)unit * NPTS + q) * RCH);
  const float g = fmaxf(fmaxf(p[0], p[1]), fmaxf(p[2], p[3]));
  const float x = qpts[3 * q], y = qpts[3 * q + 1], z = qpts[3 * q + 2];
  const float x2 = x * x + y * y + z * z;
  float d = fmaxf(fmaf(-2.0f, g, x2), 0.0f);

  #pragma unroll
  for (int off = 1; off < 64; off <<= 1) d += __shfl_xor(d, off, 64);
  __shared__ float sum4[4];
  if ((t & 63) == 0) sum4[t >> 6] = d;
  __syncthreads();
  if (t == 0) {
    const float ssum = (sum4[0] + sum4[1]) + (sum4[2] + sum4[3]);
    const int b = pair >> 2, s = pair & 3;   // pair = b*S + s, S = 4
    atomicAdd(&out[s * B + b], ssum * (1.0f / NPTS));
  }
}

extern "C" void kernel_launch(void* const* d_in, const int* in_sizes, int n_in,
                              void* d_out, int out_size, void* d_ws, size_t ws_size,
                              hipStream_t stream) {
  (void)in_sizes; (void)n_in; (void)ws_size;
  const float* out_pts = (const float*)d_in[0];
  const float* tgt_pts = (const float*)d_in[1];
  float* out = (float*)d_out;
  float* part = (float*)d_ws;   // needs UNITS*NPTS*RCH*4 = 2 MB of workspace

  hipMemsetAsync(out, 0, out_size * sizeof(float), stream);
  dim3 grid(QCH, RCH, UNITS);   // 512 blocks, 2 per CU
  chamfer_mfma_main<<<grid, THREADS, 0, stream>>>(out_pts, tgt_pts, part);
  chamfer_finalize<<<dim3(UNITS * 16), 256, 0, stream>>>(out_pts, tgt_pts, part, out);
}

// Round 2
// 87.095 us; speedup vs baseline: 1.1394x; 1.0603x over previous
//
#include <hip/hip_runtime.h>

// Chamfer distance: B=4, S=4, N=M=4096, D=3, fp32 in/out.
//
// R9: single fused kernel, ZERO workspace use. R8's rocprof showed the timed
// iteration dominated by ~40us fillBufferAligned dispatches (268 MB = the
// harness poison of d_ws) that our part-buffer + finalize kernel serialized
// behind. All cross-block combines are gone:
//   - 256 blocks = (8 query-chunks) x (32 unit = pair*2+dir), 512 thr, 8 waves.
//   - Waves 0-3 own the block's 512 queries (8 A-frags = 128 q/wave, in regs)
//     vs refs [0,2048); waves 4-7 duplicate the queries vs refs [2048,4096).
//     Per-query partial max combined through 4 KB of LDS at the end.
//   - Refs staged through one 64 KB LDS buffer in 4 chunks of 1024 records
//     (512 lo-half + 512 hi-half); next chunk's raw points prefetched into
//     registers under the MFMA loop (T14 issue-early/write-late).
// MFMA math unchanged from R8 (m89-verified 21-slot bf16 triple-split in
// mfma_f32_16x16x32_bf16; absmax was 0.0):
//   g = q.r - 0.5|r|^2 per 16x16 tile; min d2 = max(x2 - 2*max_r g, 0).
// Pipe budget/CU (1 block, 8 waves, 2/SIMD): MFMA 2x1024x4.85 = 4.1us,
// DS 1024 ds_read_b128 x12 = 5.1us, builds ~1.5us -> ~8us wall.

constexpr int B = 4, S = 4, NPTS = 4096;
constexpr int UNITS = B * S * 2;        // (pair, dir)
constexpr int THREADS = 512;            // 8 waves
constexpr int QPB = 512;                // queries per block
constexpr int QCH = NPTS / QPB;         // 8
constexpr int CHUNKS = 4;               // ref chunks of 1024 records
constexpr int AFRAGS = 8;               // 16-query tiles per wave (128 q)
constexpr unsigned short BF16_ONE = 0x3F80;

typedef __attribute__((ext_vector_type(8))) short bf16x8;
typedef __attribute__((ext_vector_type(4))) float f32x4;
typedef __attribute__((ext_vector_type(4))) unsigned int u32x4;

static __device__ inline unsigned short bf16_rne(float v) {
  unsigned int u = __builtin_bit_cast(unsigned int, v);
  u += 0x7FFFu + ((u >> 16) & 1u);
  return (unsigned short)(u >> 16);
}
static __device__ inline float bf16f(unsigned short h) {
  unsigned int u = (unsigned int)h << 16;
  return __builtin_bit_cast(float, u);
}
static __device__ inline unsigned int bpack(unsigned short lo, unsigned short hi) {
  return (unsigned int)lo | ((unsigned int)hi << 16);
}

struct Split3 { unsigned short h, m, l; };
static __device__ inline Split3 split3(float v) {
  Split3 s;
  s.h = bf16_rne(v);
  float r = v - bf16f(s.h);
  s.m = bf16_rne(r);
  r -= bf16f(s.m);
  s.l = bf16_rne(r);
  return s;
}

// Record layout (64 B per point, one 16-pt tile = 1 KB, ds_read_b128/lane):
// A k-slots 0..20: [xh xh xm xh xl xm | yh yh ym yh yl ym | zh zh zm zh zl zm | 1 1 1]
// B k-slots 0..20: [xh xm xh xl xh xm | yh ym yh yl yh ym | zh zm zh zl zh zm | wh wm wl]
static __device__ inline void write_arec(u32x4* lds, int rec,
                                         float x, float y, float z) {
  const Split3 sx = split3(x), sy = split3(y), sz = split3(z);
  u32x4* base = lds + (rec >> 4) * 64 + (rec & 15);
  base[0]  = (u32x4){bpack(sx.h, sx.h), bpack(sx.m, sx.h),
                     bpack(sx.l, sx.m), bpack(sy.h, sy.h)};
  base[16] = (u32x4){bpack(sy.m, sy.h), bpack(sy.l, sy.m),
                     bpack(sz.h, sz.h), bpack(sz.m, sz.h)};
  base[32] = (u32x4){bpack(sz.l, sz.m), bpack(BF16_ONE, BF16_ONE),
                     bpack(BF16_ONE, 0), 0u};
  base[48] = (u32x4){0u, 0u, 0u, 0u};
}
static __device__ inline void write_brec(u32x4* lds, int rec,
                                         float x, float y, float z) {
  const float w = -0.5f * (x * x + y * y + z * z);
  const Split3 sx = split3(x), sy = split3(y), sz = split3(z), sw = split3(w);
  u32x4* base = lds + (rec >> 4) * 64 + (rec & 15);
  base[0]  = (u32x4){bpack(sx.h, sx.m), bpack(sx.h, sx.l),
                     bpack(sx.h, sx.m), bpack(sy.h, sy.m)};
  base[16] = (u32x4){bpack(sy.h, sy.l), bpack(sy.h, sy.m),
                     bpack(sz.h, sz.m), bpack(sz.h, sz.l)};
  base[32] = (u32x4){bpack(sz.h, sz.m), bpack(sw.h, sw.m),
                     bpack(sw.l, 0), 0u};
  base[48] = (u32x4){0u, 0u, 0u, 0u};
}

__global__ __launch_bounds__(THREADS, 2)
void chamfer_fused(const float* __restrict__ out_pts,
                   const float* __restrict__ tgt_pts,
                   float* __restrict__ out) {
  const int t = threadIdx.x;
  const int l = t & 63;
  const int wid = t >> 6;          // 0..7; wid>>2 = ref half, wid&3 = q group
  const int qc = blockIdx.x;       // 0..7
  const int unit = blockIdx.y;     // 0..31
  const int pair = unit >> 1, dir = unit & 1;

  const float* qpts = (dir == 0 ? out_pts : tgt_pts) + (size_t)pair * NPTS * 3;
  const float* rpts = (dir == 0 ? tgt_pts : out_pts) + (size_t)pair * NPTS * 3;

  __shared__ u32x4 lds[64 * 64];   // 64 KB: 64 tiles x 16 records

  // ---- A-records for this block's 512 queries (thread t builds query t).
  float x2;
  {
    const int q = qc * QPB + t;
    const float x = qpts[3 * q], y = qpts[3 * q + 1], z = qpts[3 * q + 2];
    x2 = x * x + y * y + z * z;
    write_arec(lds, t, x, y, z);
  }

  // ---- prefetch chunk 0's two ref points (lo half + hi half).
  float nx0 = rpts[3 * t],            ny0 = rpts[3 * t + 1],            nz0 = rpts[3 * t + 2];
  float nx1 = rpts[3 * (2048 + t)],   ny1 = rpts[3 * (2048 + t) + 1],   nz1 = rpts[3 * (2048 + t) + 2];

  __syncthreads();
  bf16x8 a[AFRAGS];
  #pragma unroll
  for (int m = 0; m < AFRAGS; ++m)
    a[m] = ((const bf16x8*)lds)[((wid & 3) * AFRAGS + m) * 64 + l];

  f32x4 acc[AFRAGS];
  #pragma unroll
  for (int m = 0; m < AFRAGS; ++m)
    acc[m] = (f32x4){-3.0e38f, -3.0e38f, -3.0e38f, -3.0e38f};

  const f32x4 czero = {0.f, 0.f, 0.f, 0.f};
  const int tb = (wid >> 2) * 32;          // this wave's 32 B-tiles
  const bf16x8* bp = (const bf16x8*)lds;

  for (int c = 0; c < CHUNKS; ++c) {
    __syncthreads();                       // a-loads / prev chunk reads done
    write_brec(lds, t,       nx0, ny0, nz0);       // tiles 0..31  (lo refs)
    write_brec(lds, 512 + t, nx1, ny1, nz1);       // tiles 32..63 (hi refs)
    __syncthreads();
    if (c + 1 < CHUNKS) {                  // prefetch next chunk under MFMAs
      const int jlo = (c + 1) * 512 + t, jhi = 2048 + (c + 1) * 512 + t;
      nx0 = rpts[3 * jlo]; ny0 = rpts[3 * jlo + 1]; nz0 = rpts[3 * jlo + 2];
      nx1 = rpts[3 * jhi]; ny1 = rpts[3 * jhi + 1]; nz1 = rpts[3 * jhi + 2];
    }
    // hot loop: per 2 tiles: 2 ds_read_b128, 16 MFMA, 16 v_max3.
    for (int tt = 0; tt < 32; tt += 2) {
      const bf16x8 b0 = bp[(tb + tt) * 64 + l];
      const bf16x8 b1 = bp[(tb + tt + 1) * 64 + l];
      #pragma unroll
      for (int m = 0; m < AFRAGS; ++m) {
        const f32x4 d0 = __builtin_amdgcn_mfma_f32_16x16x32_bf16(a[m], b0, czero, 0, 0, 0);
        const f32x4 d1 = __builtin_amdgcn_mfma_f32_16x16x32_bf16(a[m], b1, czero, 0, 0, 0);
        #pragma unroll
        for (int k = 0; k < 4; ++k)
          acc[m][k] = fmaxf(fmaxf(acc[m][k], d0[k]), d1[k]);  // v_max3_f32
      }
    }
  }

  __syncthreads();                 // all waves done reading record buffer

  // ---- reduce over the 16 ref-columns (lanes within each l>>4 group).
  #pragma unroll
  for (int m = 0; m < AFRAGS; ++m) {
    #pragma unroll
    for (int k = 0; k < 4; ++k) {
      float g = acc[m][k];
      g = fmaxf(g, __shfl_xor(g, 1, 64));
      g = fmaxf(g, __shfl_xor(g, 2, 64));
      g = fmaxf(g, __shfl_xor(g, 4, 64));
      g = fmaxf(g, __shfl_xor(g, 8, 64));
      acc[m][k] = g;
    }
  }
  // each lane extracts 2 of its wave's 128 queries (static indices only).
  const int jj = l & 15, h = l >> 4;
  float v_lo = 0.f, v_hi = 0.f;
  #pragma unroll
  for (int m = 0; m < 4; ++m) {
    #pragma unroll
    for (int k = 0; k < 4; ++k) {
      const bool sel = (jj == m * 4 + k);
      v_lo = sel ? acc[m][k] : v_lo;
      v_hi = sel ? acc[m + 4][k] : v_hi;
    }
  }
  float* Sg = reinterpret_cast<float*>(lds);
  const int qloc = (wid & 3) * 128 + (jj >> 2) * 16 + h * 4 + (jj & 3);
  Sg[(wid >> 2) * 512 + qloc] = v_lo;        // ref-half partial max
  Sg[(wid >> 2) * 512 + qloc + 64] = v_hi;
  __syncthreads();

  // thread t owns query t: combine halves, finish d2, block-sum.
  const float gq = fmaxf(Sg[t], Sg[512 + t]);
  float d = fmaxf(fmaf(-2.0f, gq, x2), 0.0f);
  #pragma unroll
  for (int off = 1; off < 64; off <<= 1) d += __shfl_xor(d, off, 64);
  __syncthreads();                 // Sg reads done before reuse
  if (l == 0) Sg[wid] = d;
  __syncthreads();
  if (t == 0) {
    float ssum = 0.f;
    #pragma unroll
    for (int w = 0; w < 8; ++w) ssum += Sg[w];
    const int b = pair >> 2, s = pair & 3;   // pair = b*S + s, S = 4
    atomicAdd(&out[s * B + b], ssum * (1.0f / NPTS));
  }
}

extern "C" void kernel_launch(void* const* d_in, const int* in_sizes, int n_in,
                              void* d_out, int out_size, void* d_ws, size_t ws_size,
                              hipStream_t stream) {
  (void)in_sizes; (void)n_in; (void)d_ws; (void)ws_size;
  const float* out_pts = (const float*)d_in[0];
  const float* tgt_pts = (const float*)d_in[1];
  float* out = (float*)d_out;

  hipMemsetAsync(out, 0, out_size * sizeof(float), stream);
  dim3 grid(QCH, UNITS, 1);        // 256 blocks, 1 per CU
  chamfer_fused<<<grid, THREADS, 0, stream>>>(out_pts, tgt_pts, out);
}